// Round 13
// baseline (2126.010 us; speedup 1.0000x reference)
//
#include <hip/hip_runtime.h>
#include <math.h>

constexpr int Bv = 8, Tv = 1024, DIMC = 512, NOUTC = 513;
constexpr int Mrows = Bv * 1024;         // 8192
constexpr int LDS_S = 1056;              // padded K for istft (33*32), also row stride
constexpr float PI_F = 3.14159265358979323846f;
constexpr float TWOPI_F = 6.28318530717958647692f;

struct TapInfo { int n; int off[7]; };
struct PtrTable { _Float16* h[36]; };    // [conv*2]=hi, [conv*2+1]=lo, conv 0..17

enum { BND_NONE = 0, BND_ZERO, BND_REFLECT };

typedef _Float16 half8v __attribute__((ext_vector_type(8)));
typedef _Float16 half4v __attribute__((ext_vector_type(4)));
typedef float f32x4 __attribute__((ext_vector_type(4)));

__device__ __forceinline__ void gld_lds16(const void* g, void* l) {
  __builtin_amdgcn_global_load_lds(
      (const __attribute__((address_space(1))) unsigned int*)g,
      (__attribute__((address_space(3))) unsigned int*)l, 16, 0, 0);
}

// ============ plain fp16 MFMA GEMM, 128xTN tile, dbuf, swizzled, KS chunks ==
enum { MEPI_GELU_H = 0, MEPI_GAMMARES };

template<int EPI, int TN, int KS>
__global__ __launch_bounds__(256)
void mfma_gemm(const _Float16* __restrict__ A, int lda,
               const _Float16* __restrict__ W, int K,
               const float* __restrict__ bias,
               const float* __restrict__ aux,   // gamma
               float* __restrict__ hio,         // fp32 residual in/out
               _Float16* __restrict__ Ch,       // fp16 out
               int N, int ldc)
{
  constexpr int NFR = TN / 32;
  __shared__ _Float16 sA[2][KS * 128 * 32];
  __shared__ _Float16 sB[2][KS * TN * 32];
  const int m0 = blockIdx.x * 128;
  const int n0 = blockIdx.y * TN;
  const int tid = threadIdx.x;
  const int wid = tid >> 6, lane = tid & 63;
  const int wr = wid >> 1, wc = wid & 1;
  const int fr = lane & 15, fq = lane >> 4;

  f32x4 acc[4][NFR] = {};

  const int rbase = tid >> 2;
  const int kwS = (((tid & 3) ^ ((tid >> 3) & 3)) << 3);
  const int nst = K / (32 * KS);
  const int fqS = fq ^ ((fr >> 1) & 3);
  const int aBase = (wr * 64 + fr) * 32 + fqS * 8;
  const int bBase = (wc * (TN / 2) + fr) * 32 + fqS * 8;

  const _Float16* arow[2];
  #pragma unroll
  for (int s = 0; s < 2; ++s)
    arow[s] = A + (size_t)(m0 + s * 64 + rbase) * lda + kwS;

  auto STAGE = [&](int st, int buf) {
    #pragma unroll
    for (int ks = 0; ks < KS; ++ks) {
      const int k0 = (st * KS + ks) << 5;
      #pragma unroll
      for (int s = 0; s < 2; ++s)
        gld_lds16(arow[s] + k0,
                  (char*)&sA[buf][0] + ks * 8192 + s * 4096 + wid * 1024);
      #pragma unroll
      for (int s = 0; s < TN / 64; ++s) {
        size_t bo = (size_t)(n0 + s * 64 + rbase) * K + kwS + k0;
        gld_lds16(W + bo,
                  (char*)&sB[buf][0] + ks * (TN * 64) + s * 4096 + wid * 1024);
      }
    }
  };
  auto COMPUTE = [&](int buf) {
    #pragma unroll
    for (int ks = 0; ks < KS; ++ks) {
      half8v aF[4], bF[NFR];
      #pragma unroll
      for (int i = 0; i < 4; ++i)
        aF[i] = *(const half8v*)&sA[buf][ks * 4096 + aBase + i * 512];
      #pragma unroll
      for (int j = 0; j < NFR; ++j)
        bF[j] = *(const half8v*)&sB[buf][ks * (TN * 32) + bBase + j * 512];
      #pragma unroll
      for (int i = 0; i < 4; ++i)
        #pragma unroll
        for (int j = 0; j < NFR; ++j)
          acc[i][j] = __builtin_amdgcn_mfma_f32_16x16x32_f16(aF[i], bF[j], acc[i][j], 0, 0, 0);
    }
  };

  STAGE(0, 0);
  __syncthreads();
  int cur = 0;
  for (int st = 0; st < nst; ++st) {
    if (st + 1 < nst) STAGE(st + 1, cur ^ 1);
    COMPUTE(cur);
    __syncthreads();
    cur ^= 1;
  }

  #pragma unroll
  for (int j = 0; j < NFR; ++j) {
    const int n = n0 + wc * (TN / 2) + j * 16 + fr;
    const float bj = bias[n];
    const float gj = (EPI == MEPI_GAMMARES) ? aux[n] : 0.f;
    #pragma unroll
    for (int i = 0; i < 4; ++i) {
      const int mB = m0 + wr * 64 + i * 16 + fq * 4;
      #pragma unroll
      for (int r = 0; r < 4; ++r) {
        const int m = mB + r;
        float v = acc[i][j][r] + bj;
        if (EPI == MEPI_GELU_H) {
          v = 0.5f * v * (1.f + erff(v * 0.70710678118654752f));
          Ch[(size_t)m * ldc + n] = (_Float16)v;
        } else { // MEPI_GAMMARES
          hio[(size_t)m * ldc + n] += gj * v;
        }
      }
    }
  }
}

// ============ split-fp16 MFMA GEMM (fp32-accurate), 128xTN, dbuf, swizzled ==
enum { SEPI_F32 = 0, SEPI_LEAKY_SPLIT, SEPI_ADDRES_SPLIT,
       SEPI_GELU_SPLIT, SEPI_EXPCLIP, SEPI_TANHCW };

template<int EPI, int BND, int TN>
__global__ __launch_bounds__(256)
void mfma_gemm_split(const _Float16* __restrict__ Ah, const _Float16* __restrict__ Al, int lda,
                     const _Float16* __restrict__ Wh, const _Float16* __restrict__ Wl, int K,
                     const float* __restrict__ bias,
                     const float* __restrict__ aux,   // cumsum_w for TANHCW
                     float* __restrict__ hio,
                     float* __restrict__ Cf,
                     _Float16* __restrict__ Chh, _Float16* __restrict__ Chl,
                     int N, int ldc,
                     const _Float16* __restrict__ zpage,
                     TapInfo taps)
{
  constexpr int NFR = TN / 32;
  __shared__ _Float16 sAh[2][128 * 32];
  __shared__ _Float16 sAl[2][128 * 32];
  __shared__ _Float16 sBh[2][TN * 32];
  __shared__ _Float16 sBl[2][TN * 32];
  const int m0 = blockIdx.x * 128;
  const int n0 = blockIdx.y * TN;
  const int tid = threadIdx.x;
  const int wid = tid >> 6, lane = tid & 63;
  const int wr = wid >> 1, wc = wid & 1;
  const int fr = lane & 15, fq = lane >> 4;

  f32x4 acc[4][NFR] = {};

  const int t0 = m0 & (Tv - 1);
  const int rbase = tid >> 2;
  const int kwS = (((tid & 3) ^ ((tid >> 3) & 3)) << 3);
  const int nkc = K >> 5;
  const int NT = taps.n * nkc;
  const int fqS = fq ^ ((fr >> 1) & 3);
  const int aBase = (wr * 64 + fr) * 32 + fqS * 8;
  const int bBase = (wc * (TN / 2) + fr) * 32 + fqS * 8;

  auto STAGE = [&](int st, int buf) {
    int tap = (taps.n == 1) ? 0 : (st / nkc);
    int kc = st - tap * nkc;
    const int k0 = kc << 5;
    const int off = (BND == BND_NONE) ? 0 : taps.off[tap];
    const _Float16* Wth = Wh + (size_t)tap * N * K;
    const _Float16* Wtl = Wl + (size_t)tap * N * K;
    #pragma unroll
    for (int s = 0; s < 2; ++s) {
      int t = t0 + s * 64 + rbase + off;
      bool valid = true;
      if (BND == BND_REFLECT) t = (t < 0) ? -t : (t >= Tv ? 2 * Tv - 2 - t : t);
      else if (BND == BND_ZERO) valid = (t >= 0) && (t < Tv);
      size_t ro = (size_t)(m0 - t0 + t) * lda + kwS + k0;
      const void* sh = valid ? (const void*)(Ah + ro) : (const void*)zpage;
      const void* sl = valid ? (const void*)(Al + ro) : (const void*)zpage;
      gld_lds16(sh, (char*)&sAh[buf][0] + s * 4096 + wid * 1024);
      gld_lds16(sl, (char*)&sAl[buf][0] + s * 4096 + wid * 1024);
    }
    #pragma unroll
    for (int s = 0; s < TN / 64; ++s) {
      size_t bo = (size_t)(n0 + s * 64 + rbase) * K + kwS + k0;
      gld_lds16(Wth + bo, (char*)&sBh[buf][0] + s * 4096 + wid * 1024);
      gld_lds16(Wtl + bo, (char*)&sBl[buf][0] + s * 4096 + wid * 1024);
    }
  };

  auto COMPUTE = [&](int buf) {
    half8v ah[4], al[4], bh[NFR], bl[NFR];
    #pragma unroll
    for (int i = 0; i < 4; ++i) {
      ah[i] = *(const half8v*)&sAh[buf][aBase + i * 512];
      al[i] = *(const half8v*)&sAl[buf][aBase + i * 512];
    }
    #pragma unroll
    for (int j = 0; j < NFR; ++j) {
      bh[j] = *(const half8v*)&sBh[buf][bBase + j * 512];
      bl[j] = *(const half8v*)&sBl[buf][bBase + j * 512];
    }
    #pragma unroll
    for (int i = 0; i < 4; ++i)
      #pragma unroll
      for (int j = 0; j < NFR; ++j) {
        acc[i][j] = __builtin_amdgcn_mfma_f32_16x16x32_f16(ah[i], bh[j], acc[i][j], 0, 0, 0);
        acc[i][j] = __builtin_amdgcn_mfma_f32_16x16x32_f16(ah[i], bl[j], acc[i][j], 0, 0, 0);
        acc[i][j] = __builtin_amdgcn_mfma_f32_16x16x32_f16(al[i], bh[j], acc[i][j], 0, 0, 0);
      }
  };

  STAGE(0, 0);
  __syncthreads();
  int cur = 0;
  for (int st = 0; st < NT; ++st) {
    if (st + 1 < NT) STAGE(st + 1, cur ^ 1);
    COMPUTE(cur);
    __syncthreads();
    cur ^= 1;
  }

  #pragma unroll
  for (int j = 0; j < NFR; ++j) {
    const int n = n0 + wc * (TN / 2) + j * 16 + fr;
    const bool nok = (n < N);
    const float bj = (nok && bias) ? bias[n] : 0.f;
    const float ax = (EPI == SEPI_TANHCW && nok) ? aux[n] : 0.f;
    #pragma unroll
    for (int i = 0; i < 4; ++i) {
      const int mB = m0 + wr * 64 + i * 16 + fq * 4;
      #pragma unroll
      for (int r = 0; r < 4; ++r) {
        const int m = mB + r;
        float v = acc[i][j][r] + bj;
        if (!nok) continue;
        if (EPI == SEPI_F32) {
          Cf[(size_t)m * ldc + n] = v;
        } else if (EPI == SEPI_GELU_SPLIT) {
          v = 0.5f * v * (1.f + erff(v * 0.70710678118654752f));
          _Float16 hi = (_Float16)v;
          Chh[(size_t)m * ldc + n] = hi;
          Chl[(size_t)m * ldc + n] = (_Float16)(v - (float)hi);
        } else if (EPI == SEPI_EXPCLIP) {
          Cf[(size_t)m * ldc + n] = expf(fminf(fmaxf(v, -10.f), 10.f));
        } else if (EPI == SEPI_TANHCW) {
          Cf[(size_t)m * ldc + n] = tanhf(v) * PI_F * ax;
        }
      }
    }
  }
}

// ============ res-conv split GEMM: shared multi-tap A, swizzled, DBUF =======
// 128x64 block, 64x32 wave tiles, grid (64,8). Double-buffered (T3 2-phase):
// STAGE(k+1) issued before COMPUTE(k); single barrier per step drains it
// under the MFMA window. LDS 2 x (20KB A + 24KB B) = 88 KB.
enum { REPI_LEAKY = 0, REPI_ADDRES };

template<int EPI>
__global__ __launch_bounds__(256)
void res_gemm(const _Float16* __restrict__ Ah, const _Float16* __restrict__ Al,
              const _Float16* __restrict__ Wh, const _Float16* __restrict__ Wl,
              const float* __restrict__ bias,
              const _Float16* __restrict__ prevHi,  // residual pair (ADDRES)
              const _Float16* __restrict__ prevLo,
              _Float16* __restrict__ Chh, _Float16* __restrict__ Chl,
              const _Float16* __restrict__ zpage,
              int d)
{
  __shared__ _Float16 sAh_[2][160 * 32];
  __shared__ _Float16 sAl_[2][160 * 32];
  __shared__ _Float16 sB_[2][3 * 2 * 64 * 32];   // [tap][half][64 rows][32]
  const int m0 = blockIdx.x * 128;
  const int n0 = blockIdx.y * 64;
  const int tid = threadIdx.x;
  const int wid = tid >> 6, lane = tid & 63;
  const int wr = wid >> 1, wc = wid & 1;
  const int fr = lane & 15, fq = lane >> 4;
  const int t0 = m0 & (Tv - 1);

  f32x4 acc[4][2] = {};
  const int offs[3] = {-d, 0, d};

  auto STAGE = [&](int kc, int buf) {
    const int k0h = kc << 5;
    #pragma unroll
    for (int it = 0; it < 5; ++it) {
      int cb = it * 4 + wid;
      int half = (cb >= 10) ? 1 : 0;
      int rb = (cb - half * 10) * 16;
      int row = rb + (lane >> 2);
      int slot_g = (lane & 3) ^ ((row >> 1) & 3);
      int t = t0 - 16 + row;
      bool valid = (t >= 0) && (t < Tv);
      const _Float16* srcb = half ? Al : Ah;
      const void* src = valid
          ? (const void*)(srcb + (size_t)(m0 - t0 + t) * DIMC + k0h + slot_g * 8)
          : (const void*)(zpage + slot_g * 8);
      void* dst = (char*)(half ? &sAl_[buf][0] : &sAh_[buf][0]) + rb * 64;
      gld_lds16(src, dst);
    }
    #pragma unroll
    for (int it = 0; it < 6; ++it) {
      int cb = it * 4 + wid;
      int tap = cb >> 3;
      int r2 = cb & 7;
      int half = r2 >> 2;
      int rb = (r2 & 3) * 16;
      int row = rb + (lane >> 2);
      int slot_g = (lane & 3) ^ ((row >> 1) & 3);
      const _Float16* srcb = (half ? Wl : Wh) + (size_t)tap * 512 * 512
                           + (size_t)(n0 + row) * 512 + k0h + slot_g * 8;
      void* dst = (char*)&sB_[buf][0] + ((size_t)(tap * 2 + half) * 64 + rb) * 64;
      gld_lds16(srcb, dst);
    }
  };

  auto COMPUTE = [&](int buf) {
    #pragma unroll
    for (int tap = 0; tap < 3; ++tap) {
      const int off = offs[tap];
      half8v ah[4], al[4], bh[2], bl[2];
      #pragma unroll
      for (int i = 0; i < 4; ++i) {
        int rA = wr * 64 + i * 16 + fr + off + 16;
        int ab = rA * 64 + ((fq ^ ((rA >> 1) & 3)) * 16);
        ah[i] = *(const half8v*)((const char*)&sAh_[buf][0] + ab);
        al[i] = *(const half8v*)((const char*)&sAl_[buf][0] + ab);
      }
      #pragma unroll
      for (int j = 0; j < 2; ++j) {
        int rB = wc * 32 + j * 16 + fr;
        int bb = rB * 64 + ((fq ^ ((rB >> 1) & 3)) * 16);
        bh[j] = *(const half8v*)((const char*)&sB_[buf][0] + (tap * 2 + 0) * 4096 + bb);
        bl[j] = *(const half8v*)((const char*)&sB_[buf][0] + (tap * 2 + 1) * 4096 + bb);
      }
      #pragma unroll
      for (int i = 0; i < 4; ++i)
        #pragma unroll
        for (int j = 0; j < 2; ++j) {
          acc[i][j] = __builtin_amdgcn_mfma_f32_16x16x32_f16(ah[i], bh[j], acc[i][j], 0, 0, 0);
          acc[i][j] = __builtin_amdgcn_mfma_f32_16x16x32_f16(ah[i], bl[j], acc[i][j], 0, 0, 0);
          acc[i][j] = __builtin_amdgcn_mfma_f32_16x16x32_f16(al[i], bh[j], acc[i][j], 0, 0, 0);
        }
    }
  };

  STAGE(0, 0);
  __syncthreads();
  int cur = 0;
  for (int kc = 0; kc < 16; ++kc) {
    if (kc + 1 < 16) STAGE(kc + 1, cur ^ 1);
    COMPUTE(cur);
    __syncthreads();
    cur ^= 1;
  }

  #pragma unroll
  for (int j = 0; j < 2; ++j) {
    const int n = n0 + wc * 32 + j * 16 + fr;
    const float bj = bias[n];
    #pragma unroll
    for (int i = 0; i < 4; ++i) {
      const int mB = m0 + wr * 64 + i * 16 + fq * 4;
      #pragma unroll
      for (int r = 0; r < 4; ++r) {
        const int m = mB + r;
        float v = acc[i][j][r] + bj;
        if (EPI == REPI_LEAKY) {
          v = (v > 0.f) ? v : 0.1f * v;
          _Float16 hi = (_Float16)v;
          Chh[(size_t)m * DIMC + n] = hi;
          Chl[(size_t)m * DIMC + n] = (_Float16)(v - (float)hi);
        } else { // REPI_ADDRES: residual from split pair (read-before-write)
          size_t o = (size_t)m * DIMC + n;
          float ph = (float)prevHi[o] + (float)prevLo[o];
          float nh = ph + v;
          _Float16 hi = (_Float16)nh;
          Chh[o] = hi;
          Chl[o] = (_Float16)(nh - (float)hi);
        }
      }
    }
  }
}

// ============ conv_in split GEMM: shared 7-tap A (reflect), swizzled ========
__global__ __launch_bounds__(256)
void convin_gemm(const _Float16* __restrict__ Ah, const _Float16* __restrict__ Al,
                 const _Float16* __restrict__ Wh, const _Float16* __restrict__ Wl,
                 const float* __restrict__ bias,
                 float* __restrict__ Cf)
{
  __shared__ _Float16 sAh_[160 * 32];
  __shared__ _Float16 sAl_[160 * 32];
  __shared__ _Float16 sB_[7 * 2 * 64 * 32];   // [tap][half][64 rows][32]
  const int m0 = blockIdx.x * 128;
  const int n0 = blockIdx.y * 64;
  const int tid = threadIdx.x;
  const int wid = tid >> 6, lane = tid & 63;
  const int wr = wid >> 1, wc = wid & 1;
  const int fr = lane & 15, fq = lane >> 4;
  const int t0 = m0 & (Tv - 1);

  f32x4 acc[4][2] = {};

  for (int kc = 0; kc < 8; ++kc) {          // K = 256
    const int k0h = kc << 5;
    #pragma unroll
    for (int it = 0; it < 5; ++it) {
      int cb = it * 4 + wid;
      int half = (cb >= 10) ? 1 : 0;
      int rb = (cb - half * 10) * 16;
      int row = rb + (lane >> 2);
      int slot_g = (lane & 3) ^ ((row >> 1) & 3);
      int t = t0 - 16 + row;
      t = (t < 0) ? -t : (t >= Tv ? 2 * Tv - 2 - t : t);
      const _Float16* srcb = half ? Al : Ah;
      const void* src = srcb + (size_t)(m0 - t0 + t) * 256 + k0h + slot_g * 8;
      void* dst = (char*)(half ? sAl_ : sAh_) + rb * 64;
      gld_lds16(src, dst);
    }
    #pragma unroll
    for (int it = 0; it < 14; ++it) {
      int cb = it * 4 + wid;                // 0..55
      int tap = cb >> 3;
      int r2 = cb & 7;
      int half = r2 >> 2;
      int rb = (r2 & 3) * 16;
      int row = rb + (lane >> 2);
      int slot_g = (lane & 3) ^ ((row >> 1) & 3);
      const _Float16* srcb = (half ? Wl : Wh) + (size_t)tap * 512 * 256
                           + (size_t)(n0 + row) * 256 + k0h + slot_g * 8;
      void* dst = (char*)sB_ + ((size_t)(tap * 2 + half) * 64 + rb) * 64;
      gld_lds16(srcb, dst);
    }
    __syncthreads();

    #pragma unroll
    for (int tap = 0; tap < 7; ++tap) {
      const int off = tap - 3;
      half8v ah[4], al[4], bh[2], bl[2];
      #pragma unroll
      for (int i = 0; i < 4; ++i) {
        int rA = wr * 64 + i * 16 + fr + off + 16;
        int ab = rA * 64 + ((fq ^ ((rA >> 1) & 3)) * 16);
        ah[i] = *(const half8v*)((const char*)sAh_ + ab);
        al[i] = *(const half8v*)((const char*)sAl_ + ab);
      }
      #pragma unroll
      for (int j = 0; j < 2; ++j) {
        int rB = wc * 32 + j * 16 + fr;
        int bb = rB * 64 + ((fq ^ ((rB >> 1) & 3)) * 16);
        bh[j] = *(const half8v*)((const char*)sB_ + (tap * 2 + 0) * 4096 + bb);
        bl[j] = *(const half8v*)((const char*)sB_ + (tap * 2 + 1) * 4096 + bb);
      }
      #pragma unroll
      for (int i = 0; i < 4; ++i)
        #pragma unroll
        for (int j = 0; j < 2; ++j) {
          acc[i][j] = __builtin_amdgcn_mfma_f32_16x16x32_f16(ah[i], bh[j], acc[i][j], 0, 0, 0);
          acc[i][j] = __builtin_amdgcn_mfma_f32_16x16x32_f16(ah[i], bl[j], acc[i][j], 0, 0, 0);
          acc[i][j] = __builtin_amdgcn_mfma_f32_16x16x32_f16(al[i], bh[j], acc[i][j], 0, 0, 0);
        }
    }
    __syncthreads();
  }

  #pragma unroll
  for (int j = 0; j < 2; ++j) {
    const int n = n0 + wc * 32 + j * 16 + fr;
    const float bj = bias[n];
    #pragma unroll
    for (int i = 0; i < 4; ++i) {
      const int mB = m0 + wr * 64 + i * 16 + fq * 4;
      #pragma unroll
      for (int r = 0; r < 4; ++r) {
        const int m = mB + r;
        Cf[(size_t)m * DIMC + n] = acc[i][j][r] + bj;
      }
    }
  }
}

// depthwise conv(7,dil d) fused LayerNorm; weights repacked [k][c] coalesced
__global__ __launch_bounds__(256)
void dwln(const float* __restrict__ h, const float* __restrict__ wt,
          const float* __restrict__ bias, const float* __restrict__ g,
          const float* __restrict__ be, _Float16* __restrict__ out, int d)
{
  int wid = threadIdx.x >> 6, lane = threadIdx.x & 63;
  int m = (blockIdx.x << 2) + wid;
  int t = m & (Tv - 1);
  int bT = m - t;
  int c0 = lane * 8;
  float acc[8];
  {
    float4 b0 = *(const float4*)&bias[c0];
    float4 b1 = *(const float4*)&bias[c0 + 4];
    acc[0] = b0.x; acc[1] = b0.y; acc[2] = b0.z; acc[3] = b0.w;
    acc[4] = b1.x; acc[5] = b1.y; acc[6] = b1.z; acc[7] = b1.w;
  }
  #pragma unroll
  for (int k = 0; k < 7; ++k) {
    int tt = t + (k - 3) * d;
    if (tt < 0 || tt >= Tv) continue;
    const float* hp = &h[(size_t)(bT + tt) * DIMC + c0];
    float4 v0 = *(const float4*)hp;
    float4 v1 = *(const float4*)(hp + 4);
    const float* wp = &wt[k * DIMC + c0];
    float4 w0 = *(const float4*)wp;
    float4 w1 = *(const float4*)(wp + 4);
    float hv[8] = {v0.x, v0.y, v0.z, v0.w, v1.x, v1.y, v1.z, v1.w};
    float wv[8] = {w0.x, w0.y, w0.z, w0.w, w1.x, w1.y, w1.z, w1.w};
    #pragma unroll
    for (int q = 0; q < 8; ++q)
      acc[q] = fmaf(hv[q], wv[q], acc[q]);
  }
  float sum = 0.f;
  #pragma unroll
  for (int q = 0; q < 8; ++q) sum += acc[q];
  #pragma unroll
  for (int o = 32; o > 0; o >>= 1) sum += __shfl_xor(sum, o);
  float mean = sum * (1.f / 512.f);
  float vs = 0.f;
  #pragma unroll
  for (int q = 0; q < 8; ++q) { float dd = acc[q] - mean; vs = fmaf(dd, dd, vs); }
  #pragma unroll
  for (int o = 32; o > 0; o >>= 1) vs += __shfl_xor(vs, o);
  float rstd = rsqrtf(vs * (1.f / 512.f) + 1e-6f);
  float4 g0 = *(const float4*)&g[c0];
  float4 g1 = *(const float4*)&g[c0 + 4];
  float4 e0 = *(const float4*)&be[c0];
  float4 e1 = *(const float4*)&be[c0 + 4];
  float gv[8] = {g0.x, g0.y, g0.z, g0.w, g1.x, g1.y, g1.z, g1.w};
  float ev[8] = {e0.x, e0.y, e0.z, e0.w, e1.x, e1.y, e1.z, e1.w};
  half8v ov;
  #pragma unroll
  for (int q = 0; q < 8; ++q)
    ov[q] = (_Float16)((acc[q] - mean) * rstd * gv[q] + ev[q]);
  *(half8v*)&out[(size_t)m * DIMC + c0] = ov;
}

// repack dw weights (8,512,7) -> (8,7,512)
__global__ __launch_bounds__(256)
void repack_dw(const float* __restrict__ in, float* __restrict__ out)
{
  int idx = blockIdx.x * 256 + threadIdx.x;   // 8*512*7 = 28672
  if (idx >= 8 * 512 * 7) return;
  int l = idx / 3584;
  int r = idx - l * 3584;
  int c = r / 7, k = r - c * 7;
  out[l * 3584 + k * 512 + c] = in[idx];
}

// final LayerNorm; split fp16 pair in, split fp16 out (vectorized)
__global__ __launch_bounds__(256)
void lnorm_split(const _Float16* __restrict__ ihi, const _Float16* __restrict__ ilo,
                 const float* __restrict__ g, const float* __restrict__ be,
                 _Float16* __restrict__ ohi, _Float16* __restrict__ olo)
{
  int wid = threadIdx.x >> 6, lane = threadIdx.x & 63;
  int m = (blockIdx.x << 2) + wid;
  int c0 = lane * 8;
  half8v ha = *(const half8v*)&ihi[(size_t)m * DIMC + c0];
  half8v hb = *(const half8v*)&ilo[(size_t)m * DIMC + c0];
  float acc[8];
  #pragma unroll
  for (int q = 0; q < 8; ++q) acc[q] = (float)ha[q] + (float)hb[q];
  float sum = 0.f;
  #pragma unroll
  for (int q = 0; q < 8; ++q) sum += acc[q];
  #pragma unroll
  for (int o = 32; o > 0; o >>= 1) sum += __shfl_xor(sum, o);
  float mean = sum * (1.f / 512.f);
  float vs = 0.f;
  #pragma unroll
  for (int q = 0; q < 8; ++q) { float dd = acc[q] - mean; vs = fmaf(dd, dd, vs); }
  #pragma unroll
  for (int o = 32; o > 0; o >>= 1) vs += __shfl_xor(vs, o);
  float rstd = rsqrtf(vs * (1.f / 512.f) + 1e-6f);
  float4 g0 = *(const float4*)&g[c0];
  float4 g1 = *(const float4*)&g[c0 + 4];
  float4 e0 = *(const float4*)&be[c0];
  float4 e1 = *(const float4*)&be[c0 + 4];
  float gv[8] = {g0.x, g0.y, g0.z, g0.w, g1.x, g1.y, g1.z, g1.w};
  float ev[8] = {e0.x, e0.y, e0.z, e0.w, e1.x, e1.y, e1.z, e1.w};
  half8v hv, lv;
  #pragma unroll
  for (int q = 0; q < 8; ++q) {
    float v = (acc[q] - mean) * rstd * gv[q] + ev[q];
    _Float16 hi = (_Float16)v;
    hv[q] = hi; lv[q] = (_Float16)(v - (float)hi);
  }
  *(half8v*)&ohi[(size_t)m * DIMC + c0] = hv;
  *(half8v*)&olo[(size_t)m * DIMC + c0] = lv;
}

// h = a + b; emit split fp16 pair only (vectorized x4)
__global__ __launch_bounds__(256)
void add_split(const float* __restrict__ a, const float* __restrict__ b,
               _Float16* __restrict__ hi, _Float16* __restrict__ lo, int n)
{
  int i = (blockIdx.x * 256 + threadIdx.x) * 4;
  if (i >= n) return;
  float4 va = *(const float4*)&a[i];
  float4 vb = *(const float4*)&b[i];
  float v[4] = {va.x + vb.x, va.y + vb.y, va.z + vb.z, va.w + vb.w};
  half4v h, l;
  #pragma unroll
  for (int q = 0; q < 4; ++q) {
    _Float16 hh = (_Float16)v[q];
    h[q] = hh; l[q] = (_Float16)(v[q] - (float)hh);
  }
  *(half4v*)&hi[i] = h;
  *(half4v*)&lo[i] = l;
}

// fp32 flat -> split fp16 flat (vectorized x4; n multiple of 4)
__global__ __launch_bounds__(256)
void cvt_split(const float* __restrict__ in, _Float16* __restrict__ hi,
               _Float16* __restrict__ lo, int n)
{
  int i = (blockIdx.x * 256 + threadIdx.x) * 4;
  if (i >= n) return;
  float4 vv = *(const float4*)&in[i];
  float v[4] = {vv.x, vv.y, vv.z, vv.w};
  half4v h, l;
  #pragma unroll
  for (int q = 0; q < 4; ++q) {
    _Float16 hh = (_Float16)v[q];
    h[q] = hh; l[q] = (_Float16)(v[q] - (float)hh);
  }
  *(half4v*)&hi[i] = h;
  *(half4v*)&lo[i] = l;
}

// fp32 (rows,cols) -> split fp16 (padRows,cols), zero pad rows
__global__ __launch_bounds__(256)
void cvt_split_pad(const float* __restrict__ in, _Float16* __restrict__ hi,
                   _Float16* __restrict__ lo, int rows, int cols, int padRows)
{
  int i = blockIdx.x * 256 + threadIdx.x;
  if (i >= padRows * cols) return;
  int r = i / cols;
  float v = (r < rows) ? in[i] : 0.f;
  _Float16 h = (_Float16)v;
  hi[i] = h; lo[i] = (_Float16)(v - (float)h);
}

// fp32 flat -> plain fp16 flat (n multiple of 4)
__global__ __launch_bounds__(256)
void cvt_h(const float* __restrict__ in, _Float16* __restrict__ out, int n)
{
  int i = (blockIdx.x * 256 + threadIdx.x) * 4;
  if (i >= n) return;
  float4 v = *(const float4*)&in[i];
  half4v h;
  h[0] = (_Float16)v.x; h[1] = (_Float16)v.y;
  h[2] = (_Float16)v.z; h[3] = (_Float16)v.w;
  *(half4v*)&out[i] = h;
}

// fp32 (O,C,KT) -> split fp16 [k][o][c]  (conv_in / skip weights)
__global__ __launch_bounds__(256)
void repack_split(const float* __restrict__ in, _Float16* __restrict__ hi,
                  _Float16* __restrict__ lo, int O, int C, int KT)
{
  int idx = blockIdx.x * 256 + threadIdx.x;
  if (idx >= O * C) return;
  int o = idx / C, c = idx - o * C;
  for (int k = 0; k < KT; ++k) {
    float v = in[((size_t)o * C + c) * KT + k];
    _Float16 h = (_Float16)v;
    size_t dst = ((size_t)k * O + o) * C + c;
    hi[dst] = h; lo[dst] = (_Float16)(v - (float)h);
  }
}

// batched repack of ALL 18 res-conv weights (512x512x3) -> split [k][o][c]
__global__ __launch_bounds__(256)
void repack_all(const float* __restrict__ res_w1, const float* __restrict__ res_w2,
                PtrTable pt)
{
  int blk = blockIdx.x;            // 18 * 1024
  int conv = blk >> 10;            // 0..17
  int idx = ((blk & 1023) << 8) + threadIdx.x;  // 0..262143
  int o = idx >> 9, c = idx & 511;
  const float* src = (conv < 9) ? (res_w1 + (size_t)conv * 786432)
                                : (res_w2 + (size_t)(conv - 9) * 786432);
  _Float16* hi = pt.h[conv * 2];
  _Float16* lo = pt.h[conv * 2 + 1];
  #pragma unroll
  for (int k = 0; k < 3; ++k) {
    float v = src[((size_t)o * 512 + c) * 3 + k];
    _Float16 hh = (_Float16)v;
    size_t dst = ((size_t)k * 512 + o) * 512 + c;
    hi[dst] = hh; lo[dst] = (_Float16)(v - (float)hh);
  }
}

__global__ __launch_bounds__(256)
void zero_fill16(_Float16* __restrict__ p)
{
  int i = threadIdx.x * 8;
  #pragma unroll
  for (int q = 0; q < 8; ++q) p[i + q] = (_Float16)0.f;
}

// irfft basis (hann folded), split fp16, K padded to 1056 with zeros
__global__ __launch_bounds__(256)
void build_basis_split(const float* __restrict__ window,
                       _Float16* __restrict__ bhi, _Float16* __restrict__ blo)
{
  int n = blockIdx.x;             // 0..1023
  float wn = window[n];
  const float invN = 1.f / 1024.f;
  for (int j = threadIdx.x; j < LDS_S; j += 256) {
    float coef = 0.f;
    if (j < 513) {
      int k = j;
      if (k == 0)        coef = invN;
      else if (k == 512) coef = (n & 1) ? -invN : invN;
      else {
        int r = (k * n) & 1023;
        coef = 2.f * invN * cosf(TWOPI_F * (float)r * (1.f / 1024.f));
      }
    } else if (j < 1026) {
      int k = j - 513;
      if (k != 0 && k != 512) {
        int r = (k * n) & 1023;
        coef = -2.f * invN * sinf(TWOPI_F * (float)r * (1.f / 1024.f));
      }
    }
    float v = coef * wn;
    _Float16 hi = (_Float16)v;
    bhi[(size_t)n * LDS_S + j] = hi;
    blo[(size_t)n * LDS_S + j] = (_Float16)(v - (float)hi);
  }
}

// ---- parallel phase scan (3 kernels), 32 chunks x 32 timesteps -------------
__global__ __launch_bounds__(256)
void scan_part(const float* __restrict__ dph, float* __restrict__ psum)
{
  int b = blockIdx.x, fg = blockIdx.y;
  int w = threadIdx.x >> 6, lane = threadIdx.x & 63;
  int tc = blockIdx.z * 4 + w;         // 0..31
  int f = fg * 64 + lane;
  if (f >= NOUTC) return;
  const float* p = dph + (size_t)(b * Tv + tc * 32) * NOUTC + f;
  float s = 0.f;
  #pragma unroll 8
  for (int j = 0; j < 32; ++j) s += p[(size_t)j * NOUTC];
  psum[((size_t)b * 32 + tc) * 520 + f] = s;
}

__global__ __launch_bounds__(256)
void scan_off(float* __restrict__ psum)
{
  int idx = blockIdx.x * 256 + threadIdx.x;
  if (idx >= 8 * NOUTC) return;
  int b = idx / NOUTC, f = idx - b * NOUTC;
  float run = 0.f;
  for (int tc = 0; tc < 32; ++tc) {
    size_t o = ((size_t)b * 32 + tc) * 520 + f;
    float v = psum[o];
    psum[o] = run;
    run += v;
  }
}

__global__ __launch_bounds__(256)
void scan_emit(const float* __restrict__ dph, const float* __restrict__ mag,
               const float* __restrict__ psum,
               _Float16* __restrict__ Shi, _Float16* __restrict__ Slo)
{
  int b = blockIdx.x, fg = blockIdx.y;
  int w = threadIdx.x >> 6, lane = threadIdx.x & 63;
  int tc = blockIdx.z * 4 + w;
  int f = fg * 64 + lane;
  if (f >= NOUTC) return;
  float run = psum[((size_t)b * 32 + tc) * 520 + f];
  const size_t base = (size_t)(b * Tv + tc * 32) * NOUTC + f;
  for (int j = 0; j < 32; ++j) {
    run += dph[base + (size_t)j * NOUTC];
    float r = fmodf(run + PI_F, TWOPI_F);
    if (r < 0.f) r += TWOPI_F;
    float wph = r - PI_F;
    float mg = mag[base + (size_t)j * NOUTC];
    float sn, cs;
    sincosf(wph, &sn, &cs);
    size_t mrow = (size_t)(b * Tv + tc * 32 + j) * LDS_S;
    float vc = mg * cs, vs2 = mg * sn;
    _Float16 hc = (_Float16)vc, hs = (_Float16)vs2;
    Shi[mrow + f] = hc;        Slo[mrow + f] = (_Float16)(vc - (float)hc);
    Shi[mrow + 513 + f] = hs;  Slo[mrow + 513 + f] = (_Float16)(vs2 - (float)hs);
  }
}

// S pad columns (1026..1055): zero once
__global__ __launch_bounds__(256)
void pad_S(_Float16* __restrict__ Shi, _Float16* __restrict__ Slo)
{
  int idx = blockIdx.x * 256 + threadIdx.x;   // 8192 * 30
  if (idx >= Mrows * 30) return;
  int m = idx / 30, c = 1026 + idx % 30;
  Shi[(size_t)m * LDS_S + c] = (_Float16)0.f;
  Slo[(size_t)m * LDS_S + c] = (_Float16)0.f;
}

__global__ __launch_bounds__(256)
void ola(const float* __restrict__ frames, const float* __restrict__ window,
         float* __restrict__ out)
{
  int idx = blockIdx.x * 256 + threadIdx.x;
  if (idx >= Bv * 261888) return;
  int b = idx / 261888;
  int i = idx - b * 261888;
  int l = i + 512;
  int tmax = l >> 8; if (tmax > 1023) tmax = 1023;
  int tmin = (l >= 1023) ? ((l - 1023 + 255) >> 8) : 0;
  float acc = 0.f, env = 0.f;
  for (int t = tmin; t <= tmax; ++t) {
    int n = l - (t << 8);
    acc += frames[(size_t)(b * Tv + t) * 1024 + n];
    float wv = window[n];
    env = fmaf(wv, wv, env);
  }
  out[idx] = acc / (env > 1e-11f ? env : 1.f);
}

extern "C" void kernel_launch(void* const* d_in, const int* in_sizes, int n_in,
                              void* d_out, int out_size, void* d_ws, size_t ws_size,
                              hipStream_t stream)
{
  const float* x         = (const float*)d_in[0];
  const float* conv_in_w = (const float*)d_in[1];
  const float* conv_in_b = (const float*)d_in[2];
  const float* skip_w    = (const float*)d_in[3];
  const float* skip_b    = (const float*)d_in[4];
  const float* bb_dw_w   = (const float*)d_in[5];
  const float* bb_dw_b   = (const float*)d_in[6];
  const float* bb_ln_g   = (const float*)d_in[7];
  const float* bb_ln_b   = (const float*)d_in[8];
  const float* bb_pw1_w  = (const float*)d_in[9];
  const float* bb_pw1_b  = (const float*)d_in[10];
  const float* bb_pw2_w  = (const float*)d_in[11];
  const float* bb_pw2_b  = (const float*)d_in[12];
  const float* bb_gamma  = (const float*)d_in[13];
  const float* res_w1    = (const float*)d_in[14];
  const float* res_b1    = (const float*)d_in[15];
  const float* res_w2    = (const float*)d_in[16];
  const float* res_b2    = (const float*)d_in[17];
  const float* ln_g      = (const float*)d_in[18];
  const float* ln_b      = (const float*)d_in[19];
  const float* mag_w1    = (const float*)d_in[20];
  const float* mag_b1    = (const float*)d_in[21];
  const float* mag_w2    = (const float*)d_in[22];
  const float* mag_b2    = (const float*)d_in[23];
  const float* ph_w      = (const float*)d_in[24];
  const float* ph_b      = (const float*)d_in[25];
  const float* cumsum_w  = (const float*)d_in[26];
  const float* window    = (const float*)d_in[27];
  float* out = (float*)d_out;
  float* ws  = (float*)d_ws;

  // ---- workspace layout (float units) ----
  float* w_h     = ws;                        // 4,194,304  trunk fp32 (backbone only)
  float* w_skip  = ws + 4194304;              // 4,194,304  (later: lnorm split out)
  float* w_t4    = ws + 8388608;              // 4,194,304
  float* w_mag   = ws + 12582912;             // 4,202,496
  float* w_dph   = ws + 16785408;             // 4,202,496
  float* w_basis = ws + 20987904;             // 1,081,344
  float* w_big   = ws + 22069248;             // 8,650,752
  _Float16* t3h  = (_Float16*)w_big;          // 8192x2048 h (backbone)
  _Float16* h_hi = (_Float16*)w_big;          // res stack:
  _Float16* h_lo = h_hi + 4194304;
  _Float16* y_hi = h_hi + 8388608;
  _Float16* y_lo = h_hi + 12582912;
  _Float16* Shi  = (_Float16*)w_big;          // 8192x1056 (after res stack)
  _Float16* Slo  = Shi + 8650752;
  float* w_frames= w_h;                       // 8192x1024 spans w_h+w_skip

  _Float16* t2h  = (_Float16*)(ws + 30720000);  // backbone LN out; heads: head w
  _Float16* x_hi = (_Float16*)(ws + 32817152);
  _Float16* x_lo = (_Float16*)(ws + 33865728);
  _Float16* wA_hi= (_Float16*)(ws + 34914304);
  _Float16* wA_lo= (_Float16*)(ws + 35438592);
  _Float16* wB_hi= (_Float16*)(ws + 35962880);
  _Float16* wB_lo= (_Float16*)(ws + 36487168);
  _Float16* zpg  = (_Float16*)(ws + 37011456);
  float* w_psum  = ws + 37012480;               // 8*32*520 = 133,120 f
  float* w_dwT   = ws + 37145600;               // 8*7*512 = 28,672 f

  _Float16* wpw1h = (_Float16*)w_t4;
  _Float16* wpw2h = (_Float16*)w_mag;

  static const size_t slotOffF[18] = {
    8388608, 9175040, 9961472, 10747904, 11534336,
    12582912, 13369344, 14155776, 14942208, 15728640,
    16785408, 17571840, 18358272, 19144704, 19931136,
    32817152, 33603584,
    30720000
  };
  PtrTable pt;
  for (int cv = 0; cv < 18; ++cv) {
    _Float16* hi = (_Float16*)(ws + slotOffF[cv]);
    pt.h[cv * 2] = hi;
    pt.h[cv * 2 + 1] = hi + 786432;
  }

  _Float16* lshi = (_Float16*)w_skip;
  _Float16* lslo = lshi + 4194304;
  _Float16* t4hi = (_Float16*)w_t4;
  _Float16* t4lo = t4hi + 4194304;
  _Float16* m1hi = t2h;
  _Float16* m1lo = t2h + 262144;
  _Float16* m2hi = t2h + 524288;
  _Float16* m2lo = t2h + 851968;
  _Float16* phhi = t2h + 1179648;
  _Float16* phlo = t2h + 1507328;
  _Float16* bhi  = (_Float16*)w_basis;
  _Float16* blo  = bhi + 1081344;

  dim3 blk(256);
  TapInfo tp1{1, {0}};

  zero_fill16<<<dim3(1), blk, 0, stream>>>(zpg);
  cvt_split<<<dim3(8192 * 256 / 4 / 256), blk, 0, stream>>>(x, x_hi, x_lo, 8192 * 256);
  cvt_h<<<dim3(8388608 / 4 / 256), blk, 0, stream>>>(bb_pw1_w, wpw1h, 8388608);
  cvt_h<<<dim3(8388608 / 4 / 256), blk, 0, stream>>>(bb_pw2_w, wpw2h, 8388608);
  repack_dw<<<dim3(112), blk, 0, stream>>>(bb_dw_w, w_dwT);

  // conv_in (7-tap reflect, shared-A) -> w_h fp32
  repack_split<<<dim3(512 * 256 / 256), blk, 0, stream>>>(conv_in_w, wA_hi, wA_lo, 512, 256, 7);
  convin_gemm<<<dim3(64, 8), blk, 0, stream>>>(
      x_hi, x_lo, wA_hi, wA_lo, conv_in_b, w_h);
  // skip (1x1) -> w_skip fp32
  repack_split<<<dim3(512 * 256 / 256), blk, 0, stream>>>(skip_w, wB_hi, wB_lo, 512, 256, 1);
  mfma_gemm_split<SEPI_F32, BND_NONE, 64><<<dim3(64, 8), blk, 0, stream>>>(
      x_hi, x_lo, 256, wB_hi, wB_lo, 256, skip_b, nullptr, nullptr, w_skip, nullptr, nullptr,
      512, 512, zpg, tp1);

  // ConvNeXt backbone (plain fp16 — gamma=1e-6 damps error)
  const int dil[8] = {1, 1, 2, 2, 4, 4, 8, 8};
  for (int i = 0; i < 8; ++i) {
    dwln<<<dim3(2048), blk, 0, stream>>>(w_h, w_dwT + i * 3584, bb_dw_b + i * 512,
                                         bb_ln_g + i * 512, bb_ln_b + i * 512, t2h, dil[i]);
    mfma_gemm<MEPI_GELU_H, 128, 1><<<dim3(64, 16), blk, 0, stream>>>(
        t2h, 512, wpw1h + (size_t)i * 2048 * 512, 512, bb_pw1_b + i * 2048,
        nullptr, nullptr, t3h, 2048, 2048);
    mfma_gemm<MEPI_GAMMARES, 64, 2><<<dim3(64, 8), blk, 0, stream>>>(
        t3h, 2048, wpw2h + (size_t)i * 512 * 2048, 2048, bb_pw2_b + i * 512,
        bb_gamma + i * 512, w_h, nullptr, 512, 512);
  }
  // h = w_h + w_skip -> split pair only (pair is authoritative from here on)
  add_split<<<dim3(4194304 / 4 / 256), blk, 0, stream>>>(w_h, w_skip, h_hi, h_lo, 4194304);

  // batched repack of all res weights
  repack_all<<<dim3(18 * 1024), blk, 0, stream>>>(res_w1, res_w2, pt);

  // residual dilated stacks (split-fp16, shared-A multi-tap, double-buffered)
  const int rdil[3] = {1, 3, 5};
  for (int i = 0; i < 3; ++i)
    for (int j = 0; j < 3; ++j) {
      int d = rdil[j];
      int idx = i * 3 + j;
      res_gemm<REPI_LEAKY><<<dim3(64, 8), blk, 0, stream>>>(
          h_hi, h_lo, pt.h[idx * 2], pt.h[idx * 2 + 1],
          res_b1 + idx * 512, nullptr, nullptr, y_hi, y_lo, zpg, d);
      res_gemm<REPI_ADDRES><<<dim3(64, 8), blk, 0, stream>>>(
          y_hi, y_lo, pt.h[(9 + idx) * 2], pt.h[(9 + idx) * 2 + 1],
          res_b2 + idx * 512, h_hi, h_lo, h_hi, h_lo, zpg, 1);
    }

  // final LN from split pair -> split fp16
  lnorm_split<<<dim3(2048), blk, 0, stream>>>(h_hi, h_lo, ln_g, ln_b, lshi, lslo);

  // head weights -> split fp16 (m2/ph padded to 640 rows)
  cvt_split<<<dim3(262144 / 4 / 256), blk, 0, stream>>>(mag_w1, m1hi, m1lo, 262144);
  cvt_split_pad<<<dim3(640 * 512 / 256), blk, 0, stream>>>(mag_w2, m2hi, m2lo, 513, 512, 640);
  cvt_split_pad<<<dim3(640 * 512 / 256), blk, 0, stream>>>(ph_w, phhi, phlo, 513, 512, 640);

  // heads (split-fp16 MFMA)
  mfma_gemm_split<SEPI_GELU_SPLIT, BND_NONE, 64><<<dim3(64, 8), blk, 0, stream>>>(
      lshi, lslo, 512, m1hi, m1lo, 512, mag_b1, nullptr, nullptr, nullptr,
      t4hi, t4lo, 512, 512, zpg, tp1);
  mfma_gemm_split<SEPI_EXPCLIP, BND_NONE, 64><<<dim3(64, 10), blk, 0, stream>>>(
      t4hi, t4lo, 512, m2hi, m2lo, 512, mag_b2, nullptr, nullptr, w_mag,
      nullptr, nullptr, 513, 513, zpg, tp1);
  mfma_gemm_split<SEPI_TANHCW, BND_NONE, 64><<<dim3(64, 10), blk, 0, stream>>>(
      lshi, lslo, 512, phhi, phlo, 512, ph_b, cumsum_w, nullptr, w_dph,
      nullptr, nullptr, 513, 513, zpg, tp1);

  // synthesize
  build_basis_split<<<dim3(1024), blk, 0, stream>>>(window, bhi, blo);
  pad_S<<<dim3((Mrows * 30 + 255) / 256), blk, 0, stream>>>(Shi, Slo);
  scan_part<<<dim3(8, 9, 8), blk, 0, stream>>>(w_dph, w_psum);
  scan_off<<<dim3(17), blk, 0, stream>>>(w_psum);
  scan_emit<<<dim3(8, 9, 8), blk, 0, stream>>>(w_dph, w_mag, w_psum, Shi, Slo);
  mfma_gemm_split<SEPI_F32, BND_NONE, 128><<<dim3(64, 8), blk, 0, stream>>>(
      Shi, Slo, LDS_S, bhi, blo, LDS_S, nullptr, nullptr, nullptr, w_frames,
      nullptr, nullptr, 1024, 1024, zpg, tp1);
  ola<<<dim3((Bv * 261888 + 255) / 256), blk, 0, stream>>>(w_frames, window, out);
}

// Round 14
// 1756.027 us; speedup vs baseline: 1.2107x; 1.2107x over previous
//
#include <hip/hip_runtime.h>
#include <math.h>

constexpr int Bv = 8, Tv = 1024, DIMC = 512, NOUTC = 513;
constexpr int Mrows = Bv * 1024;         // 8192
constexpr int LDS_S = 1056;              // padded K for istft (33*32), also row stride
constexpr float PI_F = 3.14159265358979323846f;
constexpr float TWOPI_F = 6.28318530717958647692f;

struct TapInfo { int n; int off[7]; };
struct PtrTable { _Float16* h[36]; };    // [conv*2]=hi, [conv*2+1]=lo, conv 0..17

enum { BND_NONE = 0, BND_ZERO, BND_REFLECT };

typedef _Float16 half8v __attribute__((ext_vector_type(8)));
typedef _Float16 half4v __attribute__((ext_vector_type(4)));
typedef float f32x4 __attribute__((ext_vector_type(4)));

__device__ __forceinline__ void gld_lds16(const void* g, void* l) {
  __builtin_amdgcn_global_load_lds(
      (const __attribute__((address_space(1))) unsigned int*)g,
      (__attribute__((address_space(3))) unsigned int*)l, 16, 0, 0);
}

// ============ plain fp16 MFMA GEMM, 128xTN tile, dbuf, swizzled, KS chunks ==
enum { MEPI_GELU_H = 0, MEPI_GAMMARES };

template<int EPI, int TN, int KS>
__global__ __launch_bounds__(256)
void mfma_gemm(const _Float16* __restrict__ A, int lda,
               const _Float16* __restrict__ W, int K,
               const float* __restrict__ bias,
               const float* __restrict__ aux,   // gamma
               float* __restrict__ hio,         // fp32 residual in/out
               _Float16* __restrict__ Ch,       // fp16 out
               int N, int ldc)
{
  constexpr int NFR = TN / 32;
  __shared__ _Float16 sA[2][KS * 128 * 32];
  __shared__ _Float16 sB[2][KS * TN * 32];
  const int m0 = blockIdx.x * 128;
  const int n0 = blockIdx.y * TN;
  const int tid = threadIdx.x;
  const int wid = tid >> 6, lane = tid & 63;
  const int wr = wid >> 1, wc = wid & 1;
  const int fr = lane & 15, fq = lane >> 4;

  f32x4 acc[4][NFR] = {};

  const int rbase = tid >> 2;
  const int kwS = (((tid & 3) ^ ((tid >> 3) & 3)) << 3);
  const int nst = K / (32 * KS);
  const int fqS = fq ^ ((fr >> 1) & 3);
  const int aBase = (wr * 64 + fr) * 32 + fqS * 8;
  const int bBase = (wc * (TN / 2) + fr) * 32 + fqS * 8;

  const _Float16* arow[2];
  #pragma unroll
  for (int s = 0; s < 2; ++s)
    arow[s] = A + (size_t)(m0 + s * 64 + rbase) * lda + kwS;

  auto STAGE = [&](int st, int buf) {
    #pragma unroll
    for (int ks = 0; ks < KS; ++ks) {
      const int k0 = (st * KS + ks) << 5;
      #pragma unroll
      for (int s = 0; s < 2; ++s)
        gld_lds16(arow[s] + k0,
                  (char*)&sA[buf][0] + ks * 8192 + s * 4096 + wid * 1024);
      #pragma unroll
      for (int s = 0; s < TN / 64; ++s) {
        size_t bo = (size_t)(n0 + s * 64 + rbase) * K + kwS + k0;
        gld_lds16(W + bo,
                  (char*)&sB[buf][0] + ks * (TN * 64) + s * 4096 + wid * 1024);
      }
    }
  };
  auto COMPUTE = [&](int buf) {
    #pragma unroll
    for (int ks = 0; ks < KS; ++ks) {
      half8v aF[4], bF[NFR];
      #pragma unroll
      for (int i = 0; i < 4; ++i)
        aF[i] = *(const half8v*)&sA[buf][ks * 4096 + aBase + i * 512];
      #pragma unroll
      for (int j = 0; j < NFR; ++j)
        bF[j] = *(const half8v*)&sB[buf][ks * (TN * 32) + bBase + j * 512];
      #pragma unroll
      for (int i = 0; i < 4; ++i)
        #pragma unroll
        for (int j = 0; j < NFR; ++j)
          acc[i][j] = __builtin_amdgcn_mfma_f32_16x16x32_f16(aF[i], bF[j], acc[i][j], 0, 0, 0);
    }
  };

  STAGE(0, 0);
  __syncthreads();
  int cur = 0;
  for (int st = 0; st < nst; ++st) {
    if (st + 1 < nst) STAGE(st + 1, cur ^ 1);
    COMPUTE(cur);
    __syncthreads();
    cur ^= 1;
  }

  #pragma unroll
  for (int j = 0; j < NFR; ++j) {
    const int n = n0 + wc * (TN / 2) + j * 16 + fr;
    const float bj = bias[n];
    const float gj = (EPI == MEPI_GAMMARES) ? aux[n] : 0.f;
    #pragma unroll
    for (int i = 0; i < 4; ++i) {
      const int mB = m0 + wr * 64 + i * 16 + fq * 4;
      #pragma unroll
      for (int r = 0; r < 4; ++r) {
        const int m = mB + r;
        float v = acc[i][j][r] + bj;
        if (EPI == MEPI_GELU_H) {
          v = 0.5f * v * (1.f + erff(v * 0.70710678118654752f));
          Ch[(size_t)m * ldc + n] = (_Float16)v;
        } else { // MEPI_GAMMARES
          hio[(size_t)m * ldc + n] += gj * v;
        }
      }
    }
  }
}

// ============ split-fp16 MFMA GEMM (fp32-accurate), 128xTN, dbuf, swizzled ==
enum { SEPI_F32 = 0, SEPI_LEAKY_SPLIT, SEPI_ADDRES_SPLIT,
       SEPI_GELU_SPLIT, SEPI_EXPCLIP, SEPI_TANHCW };

template<int EPI, int BND, int TN>
__global__ __launch_bounds__(256)
void mfma_gemm_split(const _Float16* __restrict__ Ah, const _Float16* __restrict__ Al, int lda,
                     const _Float16* __restrict__ Wh, const _Float16* __restrict__ Wl, int K,
                     const float* __restrict__ bias,
                     const float* __restrict__ aux,   // cumsum_w for TANHCW
                     float* __restrict__ hio,
                     float* __restrict__ Cf,
                     _Float16* __restrict__ Chh, _Float16* __restrict__ Chl,
                     int N, int ldc,
                     const _Float16* __restrict__ zpage,
                     TapInfo taps)
{
  constexpr int NFR = TN / 32;
  __shared__ _Float16 sAh[2][128 * 32];
  __shared__ _Float16 sAl[2][128 * 32];
  __shared__ _Float16 sBh[2][TN * 32];
  __shared__ _Float16 sBl[2][TN * 32];
  const int m0 = blockIdx.x * 128;
  const int n0 = blockIdx.y * TN;
  const int tid = threadIdx.x;
  const int wid = tid >> 6, lane = tid & 63;
  const int wr = wid >> 1, wc = wid & 1;
  const int fr = lane & 15, fq = lane >> 4;

  f32x4 acc[4][NFR] = {};

  const int t0 = m0 & (Tv - 1);
  const int rbase = tid >> 2;
  const int kwS = (((tid & 3) ^ ((tid >> 3) & 3)) << 3);
  const int nkc = K >> 5;
  const int NT = taps.n * nkc;
  const int fqS = fq ^ ((fr >> 1) & 3);
  const int aBase = (wr * 64 + fr) * 32 + fqS * 8;
  const int bBase = (wc * (TN / 2) + fr) * 32 + fqS * 8;

  auto STAGE = [&](int st, int buf) {
    int tap = (taps.n == 1) ? 0 : (st / nkc);
    int kc = st - tap * nkc;
    const int k0 = kc << 5;
    const int off = (BND == BND_NONE) ? 0 : taps.off[tap];
    const _Float16* Wth = Wh + (size_t)tap * N * K;
    const _Float16* Wtl = Wl + (size_t)tap * N * K;
    #pragma unroll
    for (int s = 0; s < 2; ++s) {
      int t = t0 + s * 64 + rbase + off;
      bool valid = true;
      if (BND == BND_REFLECT) t = (t < 0) ? -t : (t >= Tv ? 2 * Tv - 2 - t : t);
      else if (BND == BND_ZERO) valid = (t >= 0) && (t < Tv);
      size_t ro = (size_t)(m0 - t0 + t) * lda + kwS + k0;
      const void* sh = valid ? (const void*)(Ah + ro) : (const void*)zpage;
      const void* sl = valid ? (const void*)(Al + ro) : (const void*)zpage;
      gld_lds16(sh, (char*)&sAh[buf][0] + s * 4096 + wid * 1024);
      gld_lds16(sl, (char*)&sAl[buf][0] + s * 4096 + wid * 1024);
    }
    #pragma unroll
    for (int s = 0; s < TN / 64; ++s) {
      size_t bo = (size_t)(n0 + s * 64 + rbase) * K + kwS + k0;
      gld_lds16(Wth + bo, (char*)&sBh[buf][0] + s * 4096 + wid * 1024);
      gld_lds16(Wtl + bo, (char*)&sBl[buf][0] + s * 4096 + wid * 1024);
    }
  };

  auto COMPUTE = [&](int buf) {
    half8v ah[4], al[4], bh[NFR], bl[NFR];
    #pragma unroll
    for (int i = 0; i < 4; ++i) {
      ah[i] = *(const half8v*)&sAh[buf][aBase + i * 512];
      al[i] = *(const half8v*)&sAl[buf][aBase + i * 512];
    }
    #pragma unroll
    for (int j = 0; j < NFR; ++j) {
      bh[j] = *(const half8v*)&sBh[buf][bBase + j * 512];
      bl[j] = *(const half8v*)&sBl[buf][bBase + j * 512];
    }
    #pragma unroll
    for (int i = 0; i < 4; ++i)
      #pragma unroll
      for (int j = 0; j < NFR; ++j) {
        acc[i][j] = __builtin_amdgcn_mfma_f32_16x16x32_f16(ah[i], bh[j], acc[i][j], 0, 0, 0);
        acc[i][j] = __builtin_amdgcn_mfma_f32_16x16x32_f16(ah[i], bl[j], acc[i][j], 0, 0, 0);
        acc[i][j] = __builtin_amdgcn_mfma_f32_16x16x32_f16(al[i], bh[j], acc[i][j], 0, 0, 0);
      }
  };

  STAGE(0, 0);
  __syncthreads();
  int cur = 0;
  for (int st = 0; st < NT; ++st) {
    if (st + 1 < NT) STAGE(st + 1, cur ^ 1);
    COMPUTE(cur);
    __syncthreads();
    cur ^= 1;
  }

  #pragma unroll
  for (int j = 0; j < NFR; ++j) {
    const int n = n0 + wc * (TN / 2) + j * 16 + fr;
    const bool nok = (n < N);
    const float bj = (nok && bias) ? bias[n] : 0.f;
    const float ax = (EPI == SEPI_TANHCW && nok) ? aux[n] : 0.f;
    #pragma unroll
    for (int i = 0; i < 4; ++i) {
      const int mB = m0 + wr * 64 + i * 16 + fq * 4;
      #pragma unroll
      for (int r = 0; r < 4; ++r) {
        const int m = mB + r;
        float v = acc[i][j][r] + bj;
        if (!nok) continue;
        if (EPI == SEPI_F32) {
          Cf[(size_t)m * ldc + n] = v;
        } else if (EPI == SEPI_GELU_SPLIT) {
          v = 0.5f * v * (1.f + erff(v * 0.70710678118654752f));
          _Float16 hi = (_Float16)v;
          Chh[(size_t)m * ldc + n] = hi;
          Chl[(size_t)m * ldc + n] = (_Float16)(v - (float)hi);
        } else if (EPI == SEPI_EXPCLIP) {
          Cf[(size_t)m * ldc + n] = expf(fminf(fmaxf(v, -10.f), 10.f));
        } else if (EPI == SEPI_TANHCW) {
          Cf[(size_t)m * ldc + n] = tanhf(v) * PI_F * ax;
        }
      }
    }
  }
}

// ============ res-conv split GEMM: shared multi-tap A, swizzled LDS =========
// Round-12 structure (measured best): single-buffered, 128x64 block, 64x32
// wave tiles, grid (64,8), 44 KB LDS -> 2 blocks/CU. Residual via split pair.
enum { REPI_LEAKY = 0, REPI_ADDRES };

template<int EPI>
__global__ __launch_bounds__(256)
void res_gemm(const _Float16* __restrict__ Ah, const _Float16* __restrict__ Al,
              const _Float16* __restrict__ Wh, const _Float16* __restrict__ Wl,
              const float* __restrict__ bias,
              const _Float16* __restrict__ prevHi,  // residual pair (ADDRES)
              const _Float16* __restrict__ prevLo,
              _Float16* __restrict__ Chh, _Float16* __restrict__ Chl,
              const _Float16* __restrict__ zpage,
              int d)
{
  __shared__ _Float16 sAh_[160 * 32];
  __shared__ _Float16 sAl_[160 * 32];
  __shared__ _Float16 sB_[3 * 2 * 64 * 32];   // [tap][half][64 rows][32]
  const int m0 = blockIdx.x * 128;
  const int n0 = blockIdx.y * 64;
  const int tid = threadIdx.x;
  const int wid = tid >> 6, lane = tid & 63;
  const int wr = wid >> 1, wc = wid & 1;
  const int fr = lane & 15, fq = lane >> 4;
  const int t0 = m0 & (Tv - 1);

  f32x4 acc[4][2] = {};
  const int offs[3] = {-d, 0, d};

  for (int kc = 0; kc < 16; ++kc) {
    const int k0h = kc << 5;
    #pragma unroll
    for (int it = 0; it < 5; ++it) {
      int cb = it * 4 + wid;
      int half = (cb >= 10) ? 1 : 0;
      int rb = (cb - half * 10) * 16;
      int row = rb + (lane >> 2);
      int slot_g = (lane & 3) ^ ((row >> 1) & 3);
      int t = t0 - 16 + row;
      bool valid = (t >= 0) && (t < Tv);
      const _Float16* srcb = half ? Al : Ah;
      const void* src = valid
          ? (const void*)(srcb + (size_t)(m0 - t0 + t) * DIMC + k0h + slot_g * 8)
          : (const void*)(zpage + slot_g * 8);
      void* dst = (char*)(half ? sAl_ : sAh_) + rb * 64;
      gld_lds16(src, dst);
    }
    #pragma unroll
    for (int it = 0; it < 6; ++it) {
      int cb = it * 4 + wid;
      int tap = cb >> 3;
      int r2 = cb & 7;
      int half = r2 >> 2;
      int rb = (r2 & 3) * 16;
      int row = rb + (lane >> 2);
      int slot_g = (lane & 3) ^ ((row >> 1) & 3);
      const _Float16* srcb = (half ? Wl : Wh) + (size_t)tap * 512 * 512
                           + (size_t)(n0 + row) * 512 + k0h + slot_g * 8;
      void* dst = (char*)sB_ + ((size_t)(tap * 2 + half) * 64 + rb) * 64;
      gld_lds16(srcb, dst);
    }
    __syncthreads();

    #pragma unroll
    for (int tap = 0; tap < 3; ++tap) {
      const int off = offs[tap];
      half8v ah[4], al[4], bh[2], bl[2];
      #pragma unroll
      for (int i = 0; i < 4; ++i) {
        int rA = wr * 64 + i * 16 + fr + off + 16;
        int ab = rA * 64 + ((fq ^ ((rA >> 1) & 3)) * 16);
        ah[i] = *(const half8v*)((const char*)sAh_ + ab);
        al[i] = *(const half8v*)((const char*)sAl_ + ab);
      }
      #pragma unroll
      for (int j = 0; j < 2; ++j) {
        int rB = wc * 32 + j * 16 + fr;
        int bb = rB * 64 + ((fq ^ ((rB >> 1) & 3)) * 16);
        bh[j] = *(const half8v*)((const char*)sB_ + (tap * 2 + 0) * 4096 + bb);
        bl[j] = *(const half8v*)((const char*)sB_ + (tap * 2 + 1) * 4096 + bb);
      }
      #pragma unroll
      for (int i = 0; i < 4; ++i)
        #pragma unroll
        for (int j = 0; j < 2; ++j) {
          acc[i][j] = __builtin_amdgcn_mfma_f32_16x16x32_f16(ah[i], bh[j], acc[i][j], 0, 0, 0);
          acc[i][j] = __builtin_amdgcn_mfma_f32_16x16x32_f16(ah[i], bl[j], acc[i][j], 0, 0, 0);
          acc[i][j] = __builtin_amdgcn_mfma_f32_16x16x32_f16(al[i], bh[j], acc[i][j], 0, 0, 0);
        }
    }
    __syncthreads();
  }

  #pragma unroll
  for (int j = 0; j < 2; ++j) {
    const int n = n0 + wc * 32 + j * 16 + fr;
    const float bj = bias[n];
    #pragma unroll
    for (int i = 0; i < 4; ++i) {
      const int mB = m0 + wr * 64 + i * 16 + fq * 4;
      #pragma unroll
      for (int r = 0; r < 4; ++r) {
        const int m = mB + r;
        float v = acc[i][j][r] + bj;
        if (EPI == REPI_LEAKY) {
          v = (v > 0.f) ? v : 0.1f * v;
          _Float16 hi = (_Float16)v;
          Chh[(size_t)m * DIMC + n] = hi;
          Chl[(size_t)m * DIMC + n] = (_Float16)(v - (float)hi);
        } else { // REPI_ADDRES: residual from split pair (read-before-write)
          size_t o = (size_t)m * DIMC + n;
          float ph = (float)prevHi[o] + (float)prevLo[o];
          float nh = ph + v;
          _Float16 hi = (_Float16)nh;
          Chh[o] = hi;
          Chl[o] = (_Float16)(nh - (float)hi);
        }
      }
    }
  }
}

// ============ conv_in split GEMM: shared 7-tap A (reflect), swizzled ========
__global__ __launch_bounds__(256)
void convin_gemm(const _Float16* __restrict__ Ah, const _Float16* __restrict__ Al,
                 const _Float16* __restrict__ Wh, const _Float16* __restrict__ Wl,
                 const float* __restrict__ bias,
                 float* __restrict__ Cf)
{
  __shared__ _Float16 sAh_[160 * 32];
  __shared__ _Float16 sAl_[160 * 32];
  __shared__ _Float16 sB_[7 * 2 * 64 * 32];   // [tap][half][64 rows][32]
  const int m0 = blockIdx.x * 128;
  const int n0 = blockIdx.y * 64;
  const int tid = threadIdx.x;
  const int wid = tid >> 6, lane = tid & 63;
  const int wr = wid >> 1, wc = wid & 1;
  const int fr = lane & 15, fq = lane >> 4;
  const int t0 = m0 & (Tv - 1);

  f32x4 acc[4][2] = {};

  for (int kc = 0; kc < 8; ++kc) {          // K = 256
    const int k0h = kc << 5;
    #pragma unroll
    for (int it = 0; it < 5; ++it) {
      int cb = it * 4 + wid;
      int half = (cb >= 10) ? 1 : 0;
      int rb = (cb - half * 10) * 16;
      int row = rb + (lane >> 2);
      int slot_g = (lane & 3) ^ ((row >> 1) & 3);
      int t = t0 - 16 + row;
      t = (t < 0) ? -t : (t >= Tv ? 2 * Tv - 2 - t : t);
      const _Float16* srcb = half ? Al : Ah;
      const void* src = srcb + (size_t)(m0 - t0 + t) * 256 + k0h + slot_g * 8;
      void* dst = (char*)(half ? sAl_ : sAh_) + rb * 64;
      gld_lds16(src, dst);
    }
    #pragma unroll
    for (int it = 0; it < 14; ++it) {
      int cb = it * 4 + wid;                // 0..55
      int tap = cb >> 3;
      int r2 = cb & 7;
      int half = r2 >> 2;
      int rb = (r2 & 3) * 16;
      int row = rb + (lane >> 2);
      int slot_g = (lane & 3) ^ ((row >> 1) & 3);
      const _Float16* srcb = (half ? Wl : Wh) + (size_t)tap * 512 * 256
                           + (size_t)(n0 + row) * 256 + k0h + slot_g * 8;
      void* dst = (char*)sB_ + ((size_t)(tap * 2 + half) * 64 + rb) * 64;
      gld_lds16(srcb, dst);
    }
    __syncthreads();

    #pragma unroll
    for (int tap = 0; tap < 7; ++tap) {
      const int off = tap - 3;
      half8v ah[4], al[4], bh[2], bl[2];
      #pragma unroll
      for (int i = 0; i < 4; ++i) {
        int rA = wr * 64 + i * 16 + fr + off + 16;
        int ab = rA * 64 + ((fq ^ ((rA >> 1) & 3)) * 16);
        ah[i] = *(const half8v*)((const char*)sAh_ + ab);
        al[i] = *(const half8v*)((const char*)sAl_ + ab);
      }
      #pragma unroll
      for (int j = 0; j < 2; ++j) {
        int rB = wc * 32 + j * 16 + fr;
        int bb = rB * 64 + ((fq ^ ((rB >> 1) & 3)) * 16);
        bh[j] = *(const half8v*)((const char*)sB_ + (tap * 2 + 0) * 4096 + bb);
        bl[j] = *(const half8v*)((const char*)sB_ + (tap * 2 + 1) * 4096 + bb);
      }
      #pragma unroll
      for (int i = 0; i < 4; ++i)
        #pragma unroll
        for (int j = 0; j < 2; ++j) {
          acc[i][j] = __builtin_amdgcn_mfma_f32_16x16x32_f16(ah[i], bh[j], acc[i][j], 0, 0, 0);
          acc[i][j] = __builtin_amdgcn_mfma_f32_16x16x32_f16(ah[i], bl[j], acc[i][j], 0, 0, 0);
          acc[i][j] = __builtin_amdgcn_mfma_f32_16x16x32_f16(al[i], bh[j], acc[i][j], 0, 0, 0);
        }
    }
    __syncthreads();
  }

  #pragma unroll
  for (int j = 0; j < 2; ++j) {
    const int n = n0 + wc * 32 + j * 16 + fr;
    const float bj = bias[n];
    #pragma unroll
    for (int i = 0; i < 4; ++i) {
      const int mB = m0 + wr * 64 + i * 16 + fq * 4;
      #pragma unroll
      for (int r = 0; r < 4; ++r) {
        const int m = mB + r;
        Cf[(size_t)m * DIMC + n] = acc[i][j][r] + bj;
      }
    }
  }
}

// depthwise conv(7,dil d) fused LayerNorm; weights repacked [k][c] coalesced
__global__ __launch_bounds__(256)
void dwln(const float* __restrict__ h, const float* __restrict__ wt,
          const float* __restrict__ bias, const float* __restrict__ g,
          const float* __restrict__ be, _Float16* __restrict__ out, int d)
{
  int wid = threadIdx.x >> 6, lane = threadIdx.x & 63;
  int m = (blockIdx.x << 2) + wid;
  int t = m & (Tv - 1);
  int bT = m - t;
  int c0 = lane * 8;
  float acc[8];
  {
    float4 b0 = *(const float4*)&bias[c0];
    float4 b1 = *(const float4*)&bias[c0 + 4];
    acc[0] = b0.x; acc[1] = b0.y; acc[2] = b0.z; acc[3] = b0.w;
    acc[4] = b1.x; acc[5] = b1.y; acc[6] = b1.z; acc[7] = b1.w;
  }
  #pragma unroll
  for (int k = 0; k < 7; ++k) {
    int tt = t + (k - 3) * d;
    if (tt < 0 || tt >= Tv) continue;
    const float* hp = &h[(size_t)(bT + tt) * DIMC + c0];
    float4 v0 = *(const float4*)hp;
    float4 v1 = *(const float4*)(hp + 4);
    const float* wp = &wt[k * DIMC + c0];
    float4 w0 = *(const float4*)wp;
    float4 w1 = *(const float4*)(wp + 4);
    float hv[8] = {v0.x, v0.y, v0.z, v0.w, v1.x, v1.y, v1.z, v1.w};
    float wv[8] = {w0.x, w0.y, w0.z, w0.w, w1.x, w1.y, w1.z, w1.w};
    #pragma unroll
    for (int q = 0; q < 8; ++q)
      acc[q] = fmaf(hv[q], wv[q], acc[q]);
  }
  float sum = 0.f;
  #pragma unroll
  for (int q = 0; q < 8; ++q) sum += acc[q];
  #pragma unroll
  for (int o = 32; o > 0; o >>= 1) sum += __shfl_xor(sum, o);
  float mean = sum * (1.f / 512.f);
  float vs = 0.f;
  #pragma unroll
  for (int q = 0; q < 8; ++q) { float dd = acc[q] - mean; vs = fmaf(dd, dd, vs); }
  #pragma unroll
  for (int o = 32; o > 0; o >>= 1) vs += __shfl_xor(vs, o);
  float rstd = rsqrtf(vs * (1.f / 512.f) + 1e-6f);
  float4 g0 = *(const float4*)&g[c0];
  float4 g1 = *(const float4*)&g[c0 + 4];
  float4 e0 = *(const float4*)&be[c0];
  float4 e1 = *(const float4*)&be[c0 + 4];
  float gv[8] = {g0.x, g0.y, g0.z, g0.w, g1.x, g1.y, g1.z, g1.w};
  float ev[8] = {e0.x, e0.y, e0.z, e0.w, e1.x, e1.y, e1.z, e1.w};
  half8v ov;
  #pragma unroll
  for (int q = 0; q < 8; ++q)
    ov[q] = (_Float16)((acc[q] - mean) * rstd * gv[q] + ev[q]);
  *(half8v*)&out[(size_t)m * DIMC + c0] = ov;
}

// repack dw weights (8,512,7) -> (8,7,512)
__global__ __launch_bounds__(256)
void repack_dw(const float* __restrict__ in, float* __restrict__ out)
{
  int idx = blockIdx.x * 256 + threadIdx.x;   // 8*512*7 = 28672
  if (idx >= 8 * 512 * 7) return;
  int l = idx / 3584;
  int r = idx - l * 3584;
  int c = r / 7, k = r - c * 7;
  out[l * 3584 + k * 512 + c] = in[idx];
}

// final LayerNorm; split fp16 pair in, split fp16 out (vectorized)
__global__ __launch_bounds__(256)
void lnorm_split(const _Float16* __restrict__ ihi, const _Float16* __restrict__ ilo,
                 const float* __restrict__ g, const float* __restrict__ be,
                 _Float16* __restrict__ ohi, _Float16* __restrict__ olo)
{
  int wid = threadIdx.x >> 6, lane = threadIdx.x & 63;
  int m = (blockIdx.x << 2) + wid;
  int c0 = lane * 8;
  half8v ha = *(const half8v*)&ihi[(size_t)m * DIMC + c0];
  half8v hb = *(const half8v*)&ilo[(size_t)m * DIMC + c0];
  float acc[8];
  #pragma unroll
  for (int q = 0; q < 8; ++q) acc[q] = (float)ha[q] + (float)hb[q];
  float sum = 0.f;
  #pragma unroll
  for (int q = 0; q < 8; ++q) sum += acc[q];
  #pragma unroll
  for (int o = 32; o > 0; o >>= 1) sum += __shfl_xor(sum, o);
  float mean = sum * (1.f / 512.f);
  float vs = 0.f;
  #pragma unroll
  for (int q = 0; q < 8; ++q) { float dd = acc[q] - mean; vs = fmaf(dd, dd, vs); }
  #pragma unroll
  for (int o = 32; o > 0; o >>= 1) vs += __shfl_xor(vs, o);
  float rstd = rsqrtf(vs * (1.f / 512.f) + 1e-6f);
  float4 g0 = *(const float4*)&g[c0];
  float4 g1 = *(const float4*)&g[c0 + 4];
  float4 e0 = *(const float4*)&be[c0];
  float4 e1 = *(const float4*)&be[c0 + 4];
  float gv[8] = {g0.x, g0.y, g0.z, g0.w, g1.x, g1.y, g1.z, g1.w};
  float ev[8] = {e0.x, e0.y, e0.z, e0.w, e1.x, e1.y, e1.z, e1.w};
  half8v hv, lv;
  #pragma unroll
  for (int q = 0; q < 8; ++q) {
    float v = (acc[q] - mean) * rstd * gv[q] + ev[q];
    _Float16 hi = (_Float16)v;
    hv[q] = hi; lv[q] = (_Float16)(v - (float)hi);
  }
  *(half8v*)&ohi[(size_t)m * DIMC + c0] = hv;
  *(half8v*)&olo[(size_t)m * DIMC + c0] = lv;
}

// h = a + b; emit split fp16 pair only (vectorized x4)
__global__ __launch_bounds__(256)
void add_split(const float* __restrict__ a, const float* __restrict__ b,
               _Float16* __restrict__ hi, _Float16* __restrict__ lo, int n)
{
  int i = (blockIdx.x * 256 + threadIdx.x) * 4;
  if (i >= n) return;
  float4 va = *(const float4*)&a[i];
  float4 vb = *(const float4*)&b[i];
  float v[4] = {va.x + vb.x, va.y + vb.y, va.z + vb.z, va.w + vb.w};
  half4v h, l;
  #pragma unroll
  for (int q = 0; q < 4; ++q) {
    _Float16 hh = (_Float16)v[q];
    h[q] = hh; l[q] = (_Float16)(v[q] - (float)hh);
  }
  *(half4v*)&hi[i] = h;
  *(half4v*)&lo[i] = l;
}

// fp32 flat -> split fp16 flat (vectorized x4; n multiple of 4)
__global__ __launch_bounds__(256)
void cvt_split(const float* __restrict__ in, _Float16* __restrict__ hi,
               _Float16* __restrict__ lo, int n)
{
  int i = (blockIdx.x * 256 + threadIdx.x) * 4;
  if (i >= n) return;
  float4 vv = *(const float4*)&in[i];
  float v[4] = {vv.x, vv.y, vv.z, vv.w};
  half4v h, l;
  #pragma unroll
  for (int q = 0; q < 4; ++q) {
    _Float16 hh = (_Float16)v[q];
    h[q] = hh; l[q] = (_Float16)(v[q] - (float)hh);
  }
  *(half4v*)&hi[i] = h;
  *(half4v*)&lo[i] = l;
}

// fp32 (rows,cols) -> split fp16 (padRows,cols), zero pad rows
__global__ __launch_bounds__(256)
void cvt_split_pad(const float* __restrict__ in, _Float16* __restrict__ hi,
                   _Float16* __restrict__ lo, int rows, int cols, int padRows)
{
  int i = blockIdx.x * 256 + threadIdx.x;
  if (i >= padRows * cols) return;
  int r = i / cols;
  float v = (r < rows) ? in[i] : 0.f;
  _Float16 h = (_Float16)v;
  hi[i] = h; lo[i] = (_Float16)(v - (float)h);
}

// fp32 flat -> plain fp16 flat (n multiple of 4)
__global__ __launch_bounds__(256)
void cvt_h(const float* __restrict__ in, _Float16* __restrict__ out, int n)
{
  int i = (blockIdx.x * 256 + threadIdx.x) * 4;
  if (i >= n) return;
  float4 v = *(const float4*)&in[i];
  half4v h;
  h[0] = (_Float16)v.x; h[1] = (_Float16)v.y;
  h[2] = (_Float16)v.z; h[3] = (_Float16)v.w;
  *(half4v*)&out[i] = h;
}

// fp32 (O,C,KT) -> split fp16 [k][o][c]  (conv_in / skip weights)
__global__ __launch_bounds__(256)
void repack_split(const float* __restrict__ in, _Float16* __restrict__ hi,
                  _Float16* __restrict__ lo, int O, int C, int KT)
{
  int idx = blockIdx.x * 256 + threadIdx.x;
  if (idx >= O * C) return;
  int o = idx / C, c = idx - o * C;
  for (int k = 0; k < KT; ++k) {
    float v = in[((size_t)o * C + c) * KT + k];
    _Float16 h = (_Float16)v;
    size_t dst = ((size_t)k * O + o) * C + c;
    hi[dst] = h; lo[dst] = (_Float16)(v - (float)h);
  }
}

// batched repack of ALL 18 res-conv weights (512x512x3) -> split [k][o][c]
__global__ __launch_bounds__(256)
void repack_all(const float* __restrict__ res_w1, const float* __restrict__ res_w2,
                PtrTable pt)
{
  int blk = blockIdx.x;            // 18 * 1024
  int conv = blk >> 10;            // 0..17
  int idx = ((blk & 1023) << 8) + threadIdx.x;  // 0..262143
  int o = idx >> 9, c = idx & 511;
  const float* src = (conv < 9) ? (res_w1 + (size_t)conv * 786432)
                                : (res_w2 + (size_t)(conv - 9) * 786432);
  _Float16* hi = pt.h[conv * 2];
  _Float16* lo = pt.h[conv * 2 + 1];
  #pragma unroll
  for (int k = 0; k < 3; ++k) {
    float v = src[((size_t)o * 512 + c) * 3 + k];
    _Float16 hh = (_Float16)v;
    size_t dst = ((size_t)k * 512 + o) * 512 + c;
    hi[dst] = hh; lo[dst] = (_Float16)(v - (float)hh);
  }
}

__global__ __launch_bounds__(256)
void zero_fill16(_Float16* __restrict__ p)
{
  int i = threadIdx.x * 8;
  #pragma unroll
  for (int q = 0; q < 8; ++q) p[i + q] = (_Float16)0.f;
}

// irfft basis (hann folded), split fp16, K padded to 1056 with zeros
__global__ __launch_bounds__(256)
void build_basis_split(const float* __restrict__ window,
                       _Float16* __restrict__ bhi, _Float16* __restrict__ blo)
{
  int n = blockIdx.x;             // 0..1023
  float wn = window[n];
  const float invN = 1.f / 1024.f;
  for (int j = threadIdx.x; j < LDS_S; j += 256) {
    float coef = 0.f;
    if (j < 513) {
      int k = j;
      if (k == 0)        coef = invN;
      else if (k == 512) coef = (n & 1) ? -invN : invN;
      else {
        int r = (k * n) & 1023;
        coef = 2.f * invN * cosf(TWOPI_F * (float)r * (1.f / 1024.f));
      }
    } else if (j < 1026) {
      int k = j - 513;
      if (k != 0 && k != 512) {
        int r = (k * n) & 1023;
        coef = -2.f * invN * sinf(TWOPI_F * (float)r * (1.f / 1024.f));
      }
    }
    float v = coef * wn;
    _Float16 hi = (_Float16)v;
    bhi[(size_t)n * LDS_S + j] = hi;
    blo[(size_t)n * LDS_S + j] = (_Float16)(v - (float)hi);
  }
}

// ---- parallel phase scan (3 kernels), 32 chunks x 32 timesteps -------------
__global__ __launch_bounds__(256)
void scan_part(const float* __restrict__ dph, float* __restrict__ psum)
{
  int b = blockIdx.x, fg = blockIdx.y;
  int w = threadIdx.x >> 6, lane = threadIdx.x & 63;
  int tc = blockIdx.z * 4 + w;         // 0..31
  int f = fg * 64 + lane;
  if (f >= NOUTC) return;
  const float* p = dph + (size_t)(b * Tv + tc * 32) * NOUTC + f;
  float s = 0.f;
  #pragma unroll 8
  for (int j = 0; j < 32; ++j) s += p[(size_t)j * NOUTC];
  psum[((size_t)b * 32 + tc) * 520 + f] = s;
}

__global__ __launch_bounds__(256)
void scan_off(float* __restrict__ psum)
{
  int idx = blockIdx.x * 256 + threadIdx.x;
  if (idx >= 8 * NOUTC) return;
  int b = idx / NOUTC, f = idx - b * NOUTC;
  float run = 0.f;
  for (int tc = 0; tc < 32; ++tc) {
    size_t o = ((size_t)b * 32 + tc) * 520 + f;
    float v = psum[o];
    psum[o] = run;
    run += v;
  }
}

__global__ __launch_bounds__(256)
void scan_emit(const float* __restrict__ dph, const float* __restrict__ mag,
               const float* __restrict__ psum,
               _Float16* __restrict__ Shi, _Float16* __restrict__ Slo)
{
  int b = blockIdx.x, fg = blockIdx.y;
  int w = threadIdx.x >> 6, lane = threadIdx.x & 63;
  int tc = blockIdx.z * 4 + w;
  int f = fg * 64 + lane;
  if (f >= NOUTC) return;
  float run = psum[((size_t)b * 32 + tc) * 520 + f];
  const size_t base = (size_t)(b * Tv + tc * 32) * NOUTC + f;
  for (int j = 0; j < 32; ++j) {
    run += dph[base + (size_t)j * NOUTC];
    float r = fmodf(run + PI_F, TWOPI_F);
    if (r < 0.f) r += TWOPI_F;
    float wph = r - PI_F;
    float mg = mag[base + (size_t)j * NOUTC];
    float sn, cs;
    sincosf(wph, &sn, &cs);
    size_t mrow = (size_t)(b * Tv + tc * 32 + j) * LDS_S;
    float vc = mg * cs, vs2 = mg * sn;
    _Float16 hc = (_Float16)vc, hs = (_Float16)vs2;
    Shi[mrow + f] = hc;        Slo[mrow + f] = (_Float16)(vc - (float)hc);
    Shi[mrow + 513 + f] = hs;  Slo[mrow + 513 + f] = (_Float16)(vs2 - (float)hs);
  }
}

// S pad columns (1026..1055): zero once
__global__ __launch_bounds__(256)
void pad_S(_Float16* __restrict__ Shi, _Float16* __restrict__ Slo)
{
  int idx = blockIdx.x * 256 + threadIdx.x;   // 8192 * 30
  if (idx >= Mrows * 30) return;
  int m = idx / 30, c = 1026 + idx % 30;
  Shi[(size_t)m * LDS_S + c] = (_Float16)0.f;
  Slo[(size_t)m * LDS_S + c] = (_Float16)0.f;
}

__global__ __launch_bounds__(256)
void ola(const float* __restrict__ frames, const float* __restrict__ window,
         float* __restrict__ out)
{
  int idx = blockIdx.x * 256 + threadIdx.x;
  if (idx >= Bv * 261888) return;
  int b = idx / 261888;
  int i = idx - b * 261888;
  int l = i + 512;
  int tmax = l >> 8; if (tmax > 1023) tmax = 1023;
  int tmin = (l >= 1023) ? ((l - 1023 + 255) >> 8) : 0;
  float acc = 0.f, env = 0.f;
  for (int t = tmin; t <= tmax; ++t) {
    int n = l - (t << 8);
    acc += frames[(size_t)(b * Tv + t) * 1024 + n];
    float wv = window[n];
    env = fmaf(wv, wv, env);
  }
  out[idx] = acc / (env > 1e-11f ? env : 1.f);
}

extern "C" void kernel_launch(void* const* d_in, const int* in_sizes, int n_in,
                              void* d_out, int out_size, void* d_ws, size_t ws_size,
                              hipStream_t stream)
{
  const float* x         = (const float*)d_in[0];
  const float* conv_in_w = (const float*)d_in[1];
  const float* conv_in_b = (const float*)d_in[2];
  const float* skip_w    = (const float*)d_in[3];
  const float* skip_b    = (const float*)d_in[4];
  const float* bb_dw_w   = (const float*)d_in[5];
  const float* bb_dw_b   = (const float*)d_in[6];
  const float* bb_ln_g   = (const float*)d_in[7];
  const float* bb_ln_b   = (const float*)d_in[8];
  const float* bb_pw1_w  = (const float*)d_in[9];
  const float* bb_pw1_b  = (const float*)d_in[10];
  const float* bb_pw2_w  = (const float*)d_in[11];
  const float* bb_pw2_b  = (const float*)d_in[12];
  const float* bb_gamma  = (const float*)d_in[13];
  const float* res_w1    = (const float*)d_in[14];
  const float* res_b1    = (const float*)d_in[15];
  const float* res_w2    = (const float*)d_in[16];
  const float* res_b2    = (const float*)d_in[17];
  const float* ln_g      = (const float*)d_in[18];
  const float* ln_b      = (const float*)d_in[19];
  const float* mag_w1    = (const float*)d_in[20];
  const float* mag_b1    = (const float*)d_in[21];
  const float* mag_w2    = (const float*)d_in[22];
  const float* mag_b2    = (const float*)d_in[23];
  const float* ph_w      = (const float*)d_in[24];
  const float* ph_b      = (const float*)d_in[25];
  const float* cumsum_w  = (const float*)d_in[26];
  const float* window    = (const float*)d_in[27];
  float* out = (float*)d_out;
  float* ws  = (float*)d_ws;

  // ---- workspace layout (float units) ----
  float* w_h     = ws;                        // 4,194,304  trunk fp32 (backbone only)
  float* w_skip  = ws + 4194304;              // 4,194,304  (later: lnorm split out)
  float* w_t4    = ws + 8388608;              // 4,194,304
  float* w_mag   = ws + 12582912;             // 4,202,496
  float* w_dph   = ws + 16785408;             // 4,202,496
  float* w_basis = ws + 20987904;             // 1,081,344
  float* w_big   = ws + 22069248;             // 8,650,752
  _Float16* t3h  = (_Float16*)w_big;          // 8192x2048 h (backbone)
  _Float16* h_hi = (_Float16*)w_big;          // res stack:
  _Float16* h_lo = h_hi + 4194304;
  _Float16* y_hi = h_hi + 8388608;
  _Float16* y_lo = h_hi + 12582912;
  _Float16* Shi  = (_Float16*)w_big;          // 8192x1056 (after res stack)
  _Float16* Slo  = Shi + 8650752;
  float* w_frames= w_h;                       // 8192x1024 spans w_h+w_skip

  _Float16* t2h  = (_Float16*)(ws + 30720000);  // backbone LN out; heads: head w
  _Float16* x_hi = (_Float16*)(ws + 32817152);
  _Float16* x_lo = (_Float16*)(ws + 33865728);
  _Float16* wA_hi= (_Float16*)(ws + 34914304);
  _Float16* wA_lo= (_Float16*)(ws + 35438592);
  _Float16* wB_hi= (_Float16*)(ws + 35962880);
  _Float16* wB_lo= (_Float16*)(ws + 36487168);
  _Float16* zpg  = (_Float16*)(ws + 37011456);
  float* w_psum  = ws + 37012480;               // 8*32*520 = 133,120 f
  float* w_dwT   = ws + 37145600;               // 8*7*512 = 28,672 f

  _Float16* wpw1h = (_Float16*)w_t4;
  _Float16* wpw2h = (_Float16*)w_mag;

  static const size_t slotOffF[18] = {
    8388608, 9175040, 9961472, 10747904, 11534336,
    12582912, 13369344, 14155776, 14942208, 15728640,
    16785408, 17571840, 18358272, 19144704, 19931136,
    32817152, 33603584,
    30720000
  };
  PtrTable pt;
  for (int cv = 0; cv < 18; ++cv) {
    _Float16* hi = (_Float16*)(ws + slotOffF[cv]);
    pt.h[cv * 2] = hi;
    pt.h[cv * 2 + 1] = hi + 786432;
  }

  _Float16* lshi = (_Float16*)w_skip;
  _Float16* lslo = lshi + 4194304;
  _Float16* t4hi = (_Float16*)w_t4;
  _Float16* t4lo = t4hi + 4194304;
  _Float16* m1hi = t2h;
  _Float16* m1lo = t2h + 262144;
  _Float16* m2hi = t2h + 524288;
  _Float16* m2lo = t2h + 851968;
  _Float16* phhi = t2h + 1179648;
  _Float16* phlo = t2h + 1507328;
  _Float16* bhi  = (_Float16*)w_basis;
  _Float16* blo  = bhi + 1081344;

  dim3 blk(256);
  TapInfo tp1{1, {0}};

  zero_fill16<<<dim3(1), blk, 0, stream>>>(zpg);
  cvt_split<<<dim3(8192 * 256 / 4 / 256), blk, 0, stream>>>(x, x_hi, x_lo, 8192 * 256);
  cvt_h<<<dim3(8388608 / 4 / 256), blk, 0, stream>>>(bb_pw1_w, wpw1h, 8388608);
  cvt_h<<<dim3(8388608 / 4 / 256), blk, 0, stream>>>(bb_pw2_w, wpw2h, 8388608);
  repack_dw<<<dim3(112), blk, 0, stream>>>(bb_dw_w, w_dwT);

  // conv_in (7-tap reflect, shared-A) -> w_h fp32
  repack_split<<<dim3(512 * 256 / 256), blk, 0, stream>>>(conv_in_w, wA_hi, wA_lo, 512, 256, 7);
  convin_gemm<<<dim3(64, 8), blk, 0, stream>>>(
      x_hi, x_lo, wA_hi, wA_lo, conv_in_b, w_h);
  // skip (1x1) -> w_skip fp32
  repack_split<<<dim3(512 * 256 / 256), blk, 0, stream>>>(skip_w, wB_hi, wB_lo, 512, 256, 1);
  mfma_gemm_split<SEPI_F32, BND_NONE, 64><<<dim3(64, 8), blk, 0, stream>>>(
      x_hi, x_lo, 256, wB_hi, wB_lo, 256, skip_b, nullptr, nullptr, w_skip, nullptr, nullptr,
      512, 512, zpg, tp1);

  // ConvNeXt backbone (plain fp16 — gamma=1e-6 damps error)
  const int dil[8] = {1, 1, 2, 2, 4, 4, 8, 8};
  for (int i = 0; i < 8; ++i) {
    dwln<<<dim3(2048), blk, 0, stream>>>(w_h, w_dwT + i * 3584, bb_dw_b + i * 512,
                                         bb_ln_g + i * 512, bb_ln_b + i * 512, t2h, dil[i]);
    mfma_gemm<MEPI_GELU_H, 128, 1><<<dim3(64, 16), blk, 0, stream>>>(
        t2h, 512, wpw1h + (size_t)i * 2048 * 512, 512, bb_pw1_b + i * 2048,
        nullptr, nullptr, t3h, 2048, 2048);
    mfma_gemm<MEPI_GAMMARES, 64, 2><<<dim3(64, 8), blk, 0, stream>>>(
        t3h, 2048, wpw2h + (size_t)i * 512 * 2048, 2048, bb_pw2_b + i * 512,
        bb_gamma + i * 512, w_h, nullptr, 512, 512);
  }
  // h = w_h + w_skip -> split pair only (pair is authoritative from here on)
  add_split<<<dim3(4194304 / 4 / 256), blk, 0, stream>>>(w_h, w_skip, h_hi, h_lo, 4194304);

  // batched repack of all res weights
  repack_all<<<dim3(18 * 1024), blk, 0, stream>>>(res_w1, res_w2, pt);

  // residual dilated stacks (split-fp16, shared-A multi-tap res_gemm)
  const int rdil[3] = {1, 3, 5};
  for (int i = 0; i < 3; ++i)
    for (int j = 0; j < 3; ++j) {
      int d = rdil[j];
      int idx = i * 3 + j;
      res_gemm<REPI_LEAKY><<<dim3(64, 8), blk, 0, stream>>>(
          h_hi, h_lo, pt.h[idx * 2], pt.h[idx * 2 + 1],
          res_b1 + idx * 512, nullptr, nullptr, y_hi, y_lo, zpg, d);
      res_gemm<REPI_ADDRES><<<dim3(64, 8), blk, 0, stream>>>(
          y_hi, y_lo, pt.h[(9 + idx) * 2], pt.h[(9 + idx) * 2 + 1],
          res_b2 + idx * 512, h_hi, h_lo, h_hi, h_lo, zpg, 1);
    }

  // final LN from split pair -> split fp16
  lnorm_split<<<dim3(2048), blk, 0, stream>>>(h_hi, h_lo, ln_g, ln_b, lshi, lslo);

  // head weights -> split fp16 (m2/ph padded to 640 rows)
  cvt_split<<<dim3(262144 / 4 / 256), blk, 0, stream>>>(mag_w1, m1hi, m1lo, 262144);
  cvt_split_pad<<<dim3(640 * 512 / 256), blk, 0, stream>>>(mag_w2, m2hi, m2lo, 513, 512, 640);
  cvt_split_pad<<<dim3(640 * 512 / 256), blk, 0, stream>>>(ph_w, phhi, phlo, 513, 512, 640);

  // heads (split-fp16 MFMA)
  mfma_gemm_split<SEPI_GELU_SPLIT, BND_NONE, 64><<<dim3(64, 8), blk, 0, stream>>>(
      lshi, lslo, 512, m1hi, m1lo, 512, mag_b1, nullptr, nullptr, nullptr,
      t4hi, t4lo, 512, 512, zpg, tp1);
  mfma_gemm_split<SEPI_EXPCLIP, BND_NONE, 64><<<dim3(64, 10), blk, 0, stream>>>(
      t4hi, t4lo, 512, m2hi, m2lo, 512, mag_b2, nullptr, nullptr, w_mag,
      nullptr, nullptr, 513, 513, zpg, tp1);
  mfma_gemm_split<SEPI_TANHCW, BND_NONE, 64><<<dim3(64, 10), blk, 0, stream>>>(
      lshi, lslo, 512, phhi, phlo, 512, ph_b, cumsum_w, nullptr, w_dph,
      nullptr, nullptr, 513, 513, zpg, tp1);

  // synthesize
  build_basis_split<<<dim3(1024), blk, 0, stream>>>(window, bhi, blo);
  pad_S<<<dim3((Mrows * 30 + 255) / 256), blk, 0, stream>>>(Shi, Slo);
  scan_part<<<dim3(8, 9, 8), blk, 0, stream>>>(w_dph, w_psum);
  scan_off<<<dim3(17), blk, 0, stream>>>(w_psum);
  scan_emit<<<dim3(8, 9, 8), blk, 0, stream>>>(w_dph, w_mag, w_psum, Shi, Slo);
  mfma_gemm_split<SEPI_F32, BND_NONE, 128><<<dim3(64, 8), blk, 0, stream>>>(
      Shi, Slo, LDS_S, bhi, blo, LDS_S, nullptr, nullptr, nullptr, w_frames,
      nullptr, nullptr, 1024, 1024, zpg, tp1);
  ola<<<dim3((Bv * 261888 + 255) / 256), blk, 0, stream>>>(w_frames, window, out);
}